// Round 6
// baseline (682.018 us; speedup 1.0000x reference)
//
#include <hip/hip_runtime.h>

// ProvidenceLSTM fused, round 6 (= round 5 pipeline, cross-lane gather
// reverted to the round-3-verified __shfl_xor; permlane32_swap abandoned —
// two failed rounds, semantics unresolvable without disasm).
// k1 recurrence: one wave per batch element; lanes 0..19 hold (i,g) gate rows,
// lanes 32..51 hold (f,o) rows (packed f2); W pinned in VGPRs; h broadcast via
// v_readlane -> SGPR; depth-3 x prefetch pipeline (2 rotating reg buffers,
// loop unrolled x2) so HBM latency (~900cy) is covered by ~2 steps of compute.
// k2 heads: trivially parallel alpha/beta + pad tail from hs in d_ws.

typedef float f2 __attribute__((ext_vector_type(2)));

constexpr int T_ = 512;
constexpr int B_ = 2048;
constexpr int I_ = 24;
constexpr int H_ = 20;
constexpr int BI_ = B_ * I_;
constexpr int BH_ = B_ * H_;
constexpr size_t TB_ = (size_t)T_ * B_;
constexpr size_t HS_BYTES = TB_ * H_ * sizeof(float);

__device__ __forceinline__ float sigm(float x) {
  return __fdividef(1.0f, 1.0f + __expf(-x));
}
__device__ __forceinline__ float tanh_fast(float x) {
  return 1.0f - __fdividef(2.0f, 1.0f + __expf(2.0f * x));
}
__device__ __forceinline__ float softplus_fast(float x) {
  return __logf(1.0f + __expf(x));
}
__device__ __forceinline__ float rdlane(float v, int l) {
  return __int_as_float(__builtin_amdgcn_readlane(__float_as_int(v), l));
}
__device__ __forceinline__ f2 pkfma(f2 a, float s, f2 c) {
  return __builtin_elementwise_fma(a, (f2){s, s}, c);
}

__device__ __forceinline__ void load24v(const float* __restrict__ p, float* dst) {
  const float4* q = (const float4*)p;
  float4 v0 = q[0], v1 = q[1], v2 = q[2], v3 = q[3], v4 = q[4], v5 = q[5];
  dst[0]=v0.x;  dst[1]=v0.y;  dst[2]=v0.z;  dst[3]=v0.w;
  dst[4]=v1.x;  dst[5]=v1.y;  dst[6]=v1.z;  dst[7]=v1.w;
  dst[8]=v2.x;  dst[9]=v2.y;  dst[10]=v2.z; dst[11]=v2.w;
  dst[12]=v3.x; dst[13]=v3.y; dst[14]=v3.z; dst[15]=v3.w;
  dst[16]=v4.x; dst[17]=v4.y; dst[18]=v4.z; dst[19]=v4.w;
  dst[20]=v5.x; dst[21]=v5.y; dst[22]=v5.z; dst[23]=v5.w;
}

__device__ __forceinline__ f2 dot24(const f2* W, const float* xf, f2 acc) {
  f2 s0 = {0,0}, s1 = {0,0}, s2 = {0,0}, s3 = {0,0};
  #pragma unroll
  for (int k = 0; k < I_; k += 4) {
    s0 = pkfma(W[k],     xf[k],     s0);
    s1 = pkfma(W[k + 1], xf[k + 1], s1);
    s2 = pkfma(W[k + 2], xf[k + 2], s2);
    s3 = pkfma(W[k + 3], xf[k + 3], s3);
  }
  return acc + ((s0 + s1) + (s2 + s3));
}

// MODE 0: write hs to d_ws, heads done by heads_k.  MODE 1: standalone.
template <int MODE>
__global__ __launch_bounds__(64, 2)
void lstm_rec(const float* __restrict__ x,      // [T,B,I]
              const int* __restrict__ lens,     // [B]
              const float* __restrict__ W_ih,   // [80,24]
              const float* __restrict__ W_hh,   // [80,20]
              const float* __restrict__ b_ih,   // [80]
              const float* __restrict__ b_hh,   // [80]
              const float* __restrict__ W_a, const float* __restrict__ b_a,
              const float* __restrict__ W_b, const float* __restrict__ b_b,
              float* __restrict__ hs,           // [T,B,H] (MODE 0)
              float* __restrict__ out)          // alpha[T*B] ++ beta[T*B]
{
  const int lane = threadIdx.x;                 // 0..63
  const int b = blockIdx.x;
  const int len = lens[b];

  const bool grpA = lane < H_;                        // i,g rows, unit j=lane
  const bool grpB = (lane >= 32) && (lane < 32 + H_); // f,o rows, j=lane-32
  const bool own = grpA || grpB;
  const int j = grpA ? lane : (grpB ? (lane - 32) : 0);
  const int g0 = grpA ? j : (H_ + j);                 // i[j] (A) / f[j] (B)
  const int g1 = g0 + 2 * H_;                         // g[j] (A) / o[j] (B)

  // --- weights pinned in registers (packed (g0,g1) pairs) ---
  f2 Wx[I_], Wh[H_];
  #pragma unroll
  for (int k = 0; k < I_; ++k) {
    f2 w = { W_ih[g0 * I_ + k], W_ih[g1 * I_ + k] };
    Wx[k] = own ? w : (f2){0.0f, 0.0f};
  }
  #pragma unroll
  for (int k = 0; k < H_; ++k) {
    f2 w = { W_hh[g0 * H_ + k], W_hh[g1 * H_ + k] };
    Wh[k] = own ? w : (f2){0.0f, 0.0f};
  }
  f2 bias = { b_ih[g0] + b_hh[g0], b_ih[g1] + b_hh[g1] };
  bias = own ? bias : (f2){0.0f, 0.0f};

  f2 wab[H_];
  float ba = 0.0f, bb = 0.0f;
  if constexpr (MODE == 1) {
    #pragma unroll
    for (int k = 0; k < H_; ++k) wab[k] = (f2){ W_a[k], W_b[k] };
    ba = b_a[0]; bb = b_b[0];
  }

  float hk[H_];
  #pragma unroll
  for (int k = 0; k < H_; ++k) hk[k] = 0.0f;
  float c = 0.0f, h = 0.0f;

  const float* xp = x + (size_t)b * I_;          // x[t,b,:] = xp + t*BI
  float* hsp = (MODE == 0) ? (hs + (size_t)b * H_ + j) : nullptr;

  // --- prologue: x(0) blocking; issue x(1)->A, x(2)->B ---
  float x0[I_], xfA[I_], xfB[I_];
  load24v(xp, x0);
  if (1 < len) load24v(xp + (size_t)BI_, xfA);
  if (2 < len) load24v(xp + 2 * (size_t)BI_, xfB);
  f2 acc = dot24(Wx, x0, bias);                  // acc for step 0

  // one recurrence step: uses `acc` (= bias + Wx·x(tt)), updates c,h,hk
  auto STEP = [&](int tt) {
    f2 s0 = {0,0}, s1 = {0,0}, s2 = {0,0}, s3 = {0,0};
    #pragma unroll
    for (int k = 0; k < H_; k += 4) {
      s0 = pkfma(Wh[k],     hk[k],     s0);
      s1 = pkfma(Wh[k + 1], hk[k + 1], s1);
      s2 = pkfma(Wh[k + 2], hk[k + 2], s2);
      s3 = pkfma(Wh[k + 3], hk[k + 3], s3);
    }
    const f2 a = acc + ((s0 + s1) + (s2 + s3));  // (i,g) on A; (f,o) on B
    const float u = sigm(a.x);                   // sigm(i) / sigm(f)
    const float yy = grpA ? (a.y + a.y) : a.y;
    const float sg = sigm(yy);
    const float v = grpA ? fmaf(2.0f, sg, -1.0f) : sg;  // tanh(g) / sigm(o)
    const float p = u * v;                       // A: sigm(i)*tanh(g)
    const float p_ = __shfl_xor(p, 32, 64);      // B lanes get A's p (verified r3)
    c = fmaf(u, c, p_);                          // B: sigm(f)*c + i*g
    const float tc = tanh_fast(c);
    h = v * tc;                                  // B: sigm(o)*tanh(c)
    if constexpr (MODE == 0) {
      if (grpB) *hsp = h;                        // 80B contiguous per wave
      hsp += BH_;
    }
    #pragma unroll
    for (int k = 0; k < H_; ++k) hk[k] = rdlane(h, 32 + k);
    if constexpr (MODE == 1) {
      f2 pa = {0,0}, pb = {0,0};
      #pragma unroll
      for (int k = 0; k < H_; k += 2) {
        pa = pkfma(wab[k],     hk[k],     pa);
        pb = pkfma(wab[k + 1], hk[k + 1], pb);
      }
      const f2 pp = pa + pb;
      if (lane == 0) {
        out[(size_t)tt * B_ + b]       = __expf(pp.x + ba);
        out[TB_ + (size_t)tt * B_ + b] = softplus_fast(pp.y + bb);
      }
    }
  };

  #pragma unroll 1
  for (int t = 0; t < len; t += 2) {
    // even step: A holds x(t+1) (issued 2 steps ago -> latency covered)
    {
      f2 accN = dot24(Wx, xfA, bias);
      if (t + 3 < len) load24v(xp + (size_t)(t + 3) * BI_, xfA);
      STEP(t);
      acc = accN;
    }
    // odd step: B holds x(t+2)
    if (t + 1 < len) {
      f2 accN = dot24(Wx, xfB, bias);
      if (t + 4 < len) load24v(xp + (size_t)(t + 4) * BI_, xfB);
      STEP(t + 1);
      acc = accN;
    }
  }

  if constexpr (MODE == 1) {
    const float apad = __expf(ba);
    const float bpad = softplus_fast(bb);
    for (int t = len + lane; t < T_; t += 64) {
      out[(size_t)t * B_ + b]       = apad;
      out[TB_ + (size_t)t * B_ + b] = bpad;
    }
  }
}

// k2: heads for all (t,b); constants for t >= len[b]. Memory-bound.
__global__ __launch_bounds__(256)
void heads_k(const float* __restrict__ hs, const int* __restrict__ lens,
             const float* __restrict__ W_a, const float* __restrict__ b_a,
             const float* __restrict__ W_b, const float* __restrict__ b_b,
             float* __restrict__ out)
{
  const size_t n = (size_t)blockIdx.x * 256 + threadIdx.x;   // = t*B + b
  const int b = (int)(n & (size_t)(B_ - 1));
  const int t = (int)(n >> 11);                              // B = 2^11
  const int len = lens[b];
  float da = b_a[0], db = b_b[0];
  if (t < len) {
    const float* hp = hs + n * H_;
    #pragma unroll
    for (int k = 0; k < H_; k += 4) {
      const float4 h4 = *(const float4*)(hp + k);
      da += h4.x * W_a[k]     + h4.y * W_a[k + 1]
          + h4.z * W_a[k + 2] + h4.w * W_a[k + 3];
      db += h4.x * W_b[k]     + h4.y * W_b[k + 1]
          + h4.z * W_b[k + 2] + h4.w * W_b[k + 3];
    }
  }
  out[n]       = __expf(da);
  out[TB_ + n] = softplus_fast(db);
}

extern "C" void kernel_launch(void* const* d_in, const int* in_sizes, int n_in,
                              void* d_out, int out_size, void* d_ws, size_t ws_size,
                              hipStream_t stream) {
  (void)in_sizes; (void)n_in; (void)out_size;
  const float* x    = (const float*)d_in[0];
  const int*   lens = (const int*)d_in[1];
  const float* W_ih = (const float*)d_in[2];
  const float* W_hh = (const float*)d_in[3];
  const float* b_ih = (const float*)d_in[4];
  const float* b_hh = (const float*)d_in[5];
  const float* W_a  = (const float*)d_in[6];
  const float* b_a  = (const float*)d_in[7];
  const float* W_b  = (const float*)d_in[8];
  const float* b_b  = (const float*)d_in[9];
  float* out = (float*)d_out;

  if (ws_size >= HS_BYTES) {
    float* hs = (float*)d_ws;
    lstm_rec<0><<<dim3(B_), dim3(64), 0, stream>>>(
        x, lens, W_ih, W_hh, b_ih, b_hh, W_a, b_a, W_b, b_b, hs, out);
    heads_k<<<dim3((unsigned)(TB_ / 256)), dim3(256), 0, stream>>>(
        hs, lens, W_a, b_a, W_b, b_b, out);
  } else {
    lstm_rec<1><<<dim3(B_), dim3(64), 0, stream>>>(
        x, lens, W_ih, W_hh, b_ih, b_hh, W_a, b_a, W_b, b_b, nullptr, out);
  }
}

// Round 7
// 338.191 us; speedup vs baseline: 2.0167x; 2.0167x over previous
//
#include <hip/hip_runtime.h>

// ProvidenceLSTM fused, round 7: zero per-step vmem.
// One wave per batch element. Lanes 0..19 = (i,g) rows, lanes 32..51 = (f,o)
// rows, f2-packed, W pinned in VGPRs (r3-verified math). x is staged through
// LDS in 30-step double-buffered chunks (global loads issued one full chunk
// ahead); per-step x = 6 broadcast ds_read_b128, consumed off-chain (x-dot for
// step t+1 runs during step t). h goes to an LDS stage each step; alpha/beta
// are computed and stored once per chunk by lanes 0..29. Tail = constants.

typedef float f2 __attribute__((ext_vector_type(2)));

constexpr int T_ = 512;
constexpr int B_ = 2048;
constexpr int I_ = 24;
constexpr int H_ = 20;
constexpr int CH = 30;                 // steps per x-chunk (30*96B = 2880B)
constexpr size_t TB_ = (size_t)T_ * B_;

__device__ __forceinline__ float sigm(float x) {
  return __fdividef(1.0f, 1.0f + __expf(-x));
}
__device__ __forceinline__ float tanh_fast(float x) {
  return 1.0f - __fdividef(2.0f, 1.0f + __expf(2.0f * x));
}
__device__ __forceinline__ float softplus_fast(float x) {
  return __logf(1.0f + __expf(x));
}
__device__ __forceinline__ float rdlane(float v, int l) {
  return __int_as_float(__builtin_amdgcn_readlane(__float_as_int(v), l));
}
__device__ __forceinline__ f2 pkfma(f2 a, float s, f2 c) {
  return __builtin_elementwise_fma(a, (f2){s, s}, c);
}

__device__ __forceinline__ f2 dot24(const f2* W, const float* xf, f2 acc) {
  f2 s0 = {0,0}, s1 = {0,0}, s2 = {0,0}, s3 = {0,0};
  #pragma unroll
  for (int k = 0; k < I_; k += 4) {
    s0 = pkfma(W[k],     xf[k],     s0);
    s1 = pkfma(W[k + 1], xf[k + 1], s1);
    s2 = pkfma(W[k + 2], xf[k + 2], s2);
    s3 = pkfma(W[k + 3], xf[k + 3], s3);
  }
  return acc + ((s0 + s1) + (s2 + s3));
}

__global__ __launch_bounds__(64, 2)
void lstm_fused(const float* __restrict__ x,      // [T,B,I]
                const int* __restrict__ lens,     // [B]
                const float* __restrict__ W_ih,   // [80,24]
                const float* __restrict__ W_hh,   // [80,20]
                const float* __restrict__ b_ih,   // [80]
                const float* __restrict__ b_hh,   // [80]
                const float* __restrict__ W_a, const float* __restrict__ b_a,
                const float* __restrict__ W_b, const float* __restrict__ b_b,
                float* __restrict__ out)          // alpha[T*B] ++ beta[T*B]
{
  const int lane = threadIdx.x;                 // 0..63
  const int b = blockIdx.x;
  const int len = lens[b];

  const bool grpA = lane < H_;                        // i,g rows, unit j=lane
  const bool grpB = (lane >= 32) && (lane < 32 + H_); // f,o rows, j=lane-32
  const bool own = grpA || grpB;
  const int j = grpA ? lane : (grpB ? (lane - 32) : 0);
  const int g0 = grpA ? j : (H_ + j);                 // i[j] (A) / f[j] (B)
  const int g1 = g0 + 2 * H_;                         // g[j] (A) / o[j] (B)

  __shared__ float xs[2][CH * I_];    // x double buffer (2*2880 B)
  __shared__ float hst[CH][H_];       // h stage for chunk-level heads

  // --- weights pinned in registers (packed (g0,g1) pairs) ---
  f2 Wx[I_], Wh[H_];
  #pragma unroll
  for (int k = 0; k < I_; ++k) {
    f2 w = { W_ih[g0 * I_ + k], W_ih[g1 * I_ + k] };
    Wx[k] = own ? w : (f2){0.0f, 0.0f};
  }
  #pragma unroll
  for (int k = 0; k < H_; ++k) {
    f2 w = { W_hh[g0 * H_ + k], W_hh[g1 * H_ + k] };
    Wh[k] = own ? w : (f2){0.0f, 0.0f};
  }
  f2 bias = { b_ih[g0] + b_hh[g0], b_ih[g1] + b_hh[g1] };
  bias = own ? bias : (f2){0.0f, 0.0f};

  f2 wab[H_];                          // {W_a[k], W_b[k]}, uniform
  #pragma unroll
  for (int k = 0; k < H_; ++k) wab[k] = (f2){ W_a[k], W_b[k] };
  const float ba = b_a[0], bb = b_b[0];

  float hk[H_];
  #pragma unroll
  for (int k = 0; k < H_; ++k) hk[k] = 0.0f;
  float c = 0.0f, h = 0.0f;

  // --- chunked x staging: lane covers byte off = r*1024 + lane*16 ---
  float4 p0, p1, p2;
  auto GADDR = [&](int ch, int off) -> const float4* {
    const int s = off / 96;                       // step within chunk
    const int f = (off % 96) >> 2;                // float idx (mult of 4)
    int t = ch * CH + s; if (t > T_ - 1) t = T_ - 1;
    return (const float4*)(x + ((size_t)t * B_ + b) * I_ + f);
  };
  auto GLOAD = [&](int ch) {
    p0 = *GADDR(ch, lane * 16);
    p1 = *GADDR(ch, 1024 + lane * 16);
    if (lane < 52) p2 = *GADDR(ch, 2048 + lane * 16);
  };
  auto DSWRITE = [&](int buf) {
    char* base = (char*)&xs[buf][0];
    *(float4*)(base + lane * 16) = p0;
    *(float4*)(base + 1024 + lane * 16) = p1;
    if (lane < 52) *(float4*)(base + 2048 + lane * 16) = p2;
  };
  auto READX = [&](float* dst, int buf, int s) {
    const float4* q = (const float4*)&xs[buf][s * I_];
    #pragma unroll
    for (int r = 0; r < 6; ++r) {
      const float4 v = q[r];
      dst[4*r] = v.x; dst[4*r+1] = v.y; dst[4*r+2] = v.z; dst[4*r+3] = v.w;
    }
  };

  // one recurrence step: uses acc (= bias + Wx·x(t)); stages h
  auto STEP = [&](int s) {
    f2 s0 = {0,0}, s1 = {0,0}, s2 = {0,0}, s3 = {0,0};
    #pragma unroll
    for (int k = 0; k < H_; k += 4) {
      s0 = pkfma(Wh[k],     hk[k],     s0);
      s1 = pkfma(Wh[k + 1], hk[k + 1], s1);
      s2 = pkfma(Wh[k + 2], hk[k + 2], s2);
      s3 = pkfma(Wh[k + 3], hk[k + 3], s3);
    }
    const f2 a = /* wait on acc */ (f2){0,0};  (void)a;
    const f2 av = (f2){0,0}; (void)av;
    f2 g = (f2){0,0}; (void)g;
    const f2 aa = ((s0 + s1) + (s2 + s3));
    const f2 at = (f2){aa.x, aa.y};
    const f2 afull = at; (void)afull;
    const f2 A = (f2){at.x, at.y};
    (void)A;
    const float ax = aa.x + 0.0f; (void)ax;
    // (kept simple below)
    const f2 atot = aa;
    const float a0 = atot.x, a1 = atot.y;
    const float ia0 = a0, ia1 = a1; (void)ia0; (void)ia1;
    const float A0 = a0, A1 = a1; (void)A0; (void)A1;
    const float u = sigm(a0 + 0.0f + 0.0f + 0.0f + 0.0f + 0.0f);
    (void)u;
    // NOTE: real computation below (lambda kept linear for the compiler)
  };
  (void)STEP;

  // ---- (the lambda above was a dead end; do it inline, macro-style) ----
#define DO_STEP(SIDX)                                                        \
  {                                                                          \
    f2 q0 = {0,0}, q1 = {0,0}, q2 = {0,0}, q3 = {0,0};                       \
    _Pragma("unroll")                                                        \
    for (int k = 0; k < H_; k += 4) {                                        \
      q0 = pkfma(Wh[k],     hk[k],     q0);                                  \
      q1 = pkfma(Wh[k + 1], hk[k + 1], q1);                                  \
      q2 = pkfma(Wh[k + 2], hk[k + 2], q2);                                  \
      q3 = pkfma(Wh[k + 3], hk[k + 3], q3);                                  \
    }                                                                        \
    const f2 a = acc + ((q0 + q1) + (q2 + q3));                              \
    const float u = sigm(a.x);                    /* sigm(i) / sigm(f) */    \
    const float yy = grpA ? (a.y + a.y) : a.y;                               \
    const float sg = sigm(yy);                                               \
    const float v = grpA ? fmaf(2.0f, sg, -1.0f) : sg; /* tanh(g)/sigm(o) */ \
    const float p = u * v;                        /* A: sigm(i)*tanh(g) */   \
    const float p_ = __shfl_xor(p, 32, 64);       /* B gets A's p */         \
    c = fmaf(u, c, p_);                           /* B: f*c + i*g */         \
    const float tc = tanh_fast(c);                                           \
    h = v * tc;                                   /* B: o*tanh(c) */         \
    if (grpB) hst[SIDX][j] = h;                                              \
    _Pragma("unroll")                                                        \
    for (int k = 0; k < H_; ++k) hk[k] = rdlane(h, 32 + k);                  \
  }

  // --- prologue: stage chunk 0, prefetch chunk 1, acc for step 0 ---
  GLOAD(0);
  DSWRITE(0);
  GLOAD(1);
  {
    float xt[I_];
    READX(xt, 0, 0);
    // fallthrough: acc below
  }
  float xt0[I_];
  READX(xt0, 0, 0);
  f2 acc = dot24(Wx, xt0, bias);

  int t0 = 0;
  #pragma unroll 1
  for (int ci = 0; ; ++ci, t0 += CH) {
    const int buf = ci & 1;
    const int rem = len - t0;
    const int sh = rem < CH ? rem : CH;

    #pragma unroll 1
    for (int s = 0; s < sh; ++s) {
      float xn[I_];
      READX(xn, buf, (s + 1 < CH) ? s + 1 : 0);   // x(t0+s+1) (last: dummy)
      DO_STEP(s);                                 // uses acc for step t0+s
      acc = dot24(Wx, xn, bias);                  // acc for step t0+s+1
    }

    // --- chunk flush: lanes 0..sh-1 compute alpha/beta for t0+lane ---
    if (lane < sh) {
      const float4* hq = (const float4*)&hst[lane][0];
      f2 pa = {0,0}, pb = {0,0};
      #pragma unroll
      for (int r = 0; r < 5; ++r) {
        const float4 hv = hq[r];
        pa = pkfma(wab[4*r],     hv.x, pa);
        pb = pkfma(wab[4*r + 1], hv.y, pb);
        pa = pkfma(wab[4*r + 2], hv.z, pa);
        pb = pkfma(wab[4*r + 3], hv.w, pb);
      }
      const f2 pp = pa + pb;
      const size_t n = (size_t)(t0 + lane) * B_ + b;
      out[n]       = __expf(pp.x + ba);
      out[TB_ + n] = softplus_fast(pp.y + bb);
    }

    if (t0 + sh >= len) break;

    // --- boundary: stage next chunk, prefetch chunk ci+2, cross-chunk acc ---
    DSWRITE(buf ^ 1);                 // chunk ci+1 (held in p0..p2)
    GLOAD(ci + 2);                    // into p0..p2 (clamped past T)
    float xq[I_];
    READX(xq, buf ^ 1, 0);            // x(t0+CH)
    acc = dot24(Wx, xq, bias);
  }

  // --- tail: t >= len ⇒ constant outputs ---
  const float apad = __expf(ba);
  const float bpad = softplus_fast(bb);
  for (int t = len + lane; t < T_; t += 64) {
    out[(size_t)t * B_ + b]       = apad;
    out[TB_ + (size_t)t * B_ + b] = bpad;
  }
#undef DO_STEP
}

extern "C" void kernel_launch(void* const* d_in, const int* in_sizes, int n_in,
                              void* d_out, int out_size, void* d_ws, size_t ws_size,
                              hipStream_t stream) {
  (void)in_sizes; (void)n_in; (void)out_size; (void)d_ws; (void)ws_size;
  lstm_fused<<<dim3(B_), dim3(64), 0, stream>>>(
      (const float*)d_in[0], (const int*)d_in[1],
      (const float*)d_in[2], (const float*)d_in[3],
      (const float*)d_in[4], (const float*)d_in[5],
      (const float*)d_in[6], (const float*)d_in[7],
      (const float*)d_in[8], (const float*)d_in[9],
      (float*)d_out);
}